// Round 1
// baseline (696.809 us; speedup 1.0000x reference)
//
#include <hip/hip_runtime.h>

#define Bv 64
#define Tv 2048
#define Hv 1024
#define Uv 128
#define Mv 512
#define TTv 32
#define MCv 64

// ---------------- prep: pq[b,u] = query[b,:] @ Wq + bq ----------------
__global__ __launch_bounds__(128) void pq_kernel(const float* __restrict__ query,
                                                 const float* __restrict__ Wq,
                                                 const float* __restrict__ bq,
                                                 float* __restrict__ pq) {
  const int b = blockIdx.x, c = blockIdx.y, u = threadIdx.x;
  float acc = (c == 0) ? bq[u] : 0.0f;
  const float* q  = query + b * Hv + c * 128;
  const float* wq = Wq + (size_t)c * 128 * Uv;
  #pragma unroll 8
  for (int h = 0; h < 128; ++h) acc = fmaf(q[h], wq[h * Uv + u], acc);
  unsafeAtomicAdd(&pq[b * Uv + u], acc);
}

// ---------------- prep: fold conv into location projection ----------------
// W2[k,u] = sum_f conv_w[f,k] * Wl[f,u];  bias2[u] = bl[u] + sum_f conv_b[f]*Wl[f,u]
__global__ __launch_bounds__(128) void w2_kernel(const float* __restrict__ Wl,
                                                 const float* __restrict__ bl,
                                                 const float* __restrict__ conv_w,
                                                 const float* __restrict__ conv_b,
                                                 float* __restrict__ W2,
                                                 float* __restrict__ bias2) {
  const int u = threadIdx.x;
  float wl[32];
  #pragma unroll
  for (int f = 0; f < 32; ++f) wl[f] = Wl[f * Uv + u];
  for (int k = 0; k < 31; ++k) {
    float acc = 0.0f;
    #pragma unroll
    for (int f = 0; f < 32; ++f) acc = fmaf(conv_w[f * 31 + k], wl[f], acc);
    W2[k * Uv + u] = acc;
  }
  float acc = bl[u];
  #pragma unroll
  for (int f = 0; f < 32; ++f) acc = fmaf(conv_b[f], wl[f], acc);
  bias2[u] = acc;
}

// ---------------- main fused kernel ----------------
// One block: batch b, t-tile of 32. Computes pm tile (32x128) via fp32 GEMM,
// adds pq + pl (folded conv), does We GEMV + tanh + va-dot -> energy,
// sigmoid -> sg, accumulates P0 += prev_cum*pm, P1 += sg*pm, Ssg += sg.
__global__ __launch_bounds__(256) void main_kernel(
    const float* __restrict__ state, const float* __restrict__ prev_cum,
    const float* __restrict__ memory, const float* __restrict__ Wm,
    const float* __restrict__ bm, const float* __restrict__ We,
    const float* __restrict__ be, const float* __restrict__ va,
    const float* __restrict__ pq, const float* __restrict__ W2g,
    const float* __restrict__ bias2g,
    float* __restrict__ P0, float* __restrict__ P1, float* __restrict__ Ssg) {
  const int tid = threadIdx.x;
  const int tx = tid & 31;       // u-group: u0 = 4*tx
  const int ty = tid >> 5;       // 0..7 : t-group: t = 4*ty + i
  const int u0 = tx * 4;
  const int b  = blockIdx.y;
  const int t0 = blockIdx.x * TTv;

  __shared__ float sA[TTv * 68];    // memory tile [t][m'] stride 68 (16B aligned rows)
  __shared__ float sB[MCv * 132];   // Wm chunk   [m'][u] stride 132
  __shared__ float sW2[31 * Uv];
  __shared__ float sS[TTv * 132];   // s = pq+pl+pm tile [t][u]
  __shared__ float sState[92];
  __shared__ float blkP0[Uv];
  __shared__ float blkP1[Uv];
  __shared__ float blkSsg;

  if (tid < Uv) { blkP0[tid] = 0.0f; blkP1[tid] = 0.0f; }
  if (tid == Uv) blkSsg = 0.0f;

  for (int idx = tid; idx < 31 * Uv; idx += 256) sW2[idx] = W2g[idx];
  for (int j = tid; j < 92; j += 256) {
    int t = t0 - 30 + j;
    sState[j] = (t >= 0 && t < Tv) ? state[b * Tv + t] : 0.0f;
  }

  float acc[4][4];
  #pragma unroll
  for (int i = 0; i < 4; ++i) {
    #pragma unroll
    for (int j = 0; j < 4; ++j) acc[i][j] = 0.0f;
  }

  const float* memB = memory + (size_t)b * Tv * Mv + (size_t)t0 * Mv;

  for (int mc = 0; mc < Mv; mc += MCv) {
    // stage A: 32 t x 64 m  (2 float4 per thread)
    #pragma unroll
    for (int p = 0; p < 2; ++p) {
      int idx4 = tid + p * 256;
      int t  = idx4 >> 4;
      int c4 = idx4 & 15;
      float4 v = *(const float4*)(memB + (size_t)t * Mv + mc + c4 * 4);
      *(float4*)&sA[t * 68 + c4 * 4] = v;
    }
    // stage B: 64 m x 128 u (8 float4 per thread)
    #pragma unroll
    for (int p = 0; p < 8; ++p) {
      int idx4 = tid + p * 256;
      int m  = idx4 >> 5;
      int c4 = idx4 & 31;
      float4 v = *(const float4*)(Wm + (size_t)(mc + m) * Uv + c4 * 4);
      *(float4*)&sB[m * 132 + c4 * 4] = v;
    }
    __syncthreads();

    for (int m = 0; m < MCv; m += 4) {
      float a_[4][4];
      #pragma unroll
      for (int i = 0; i < 4; ++i) {
        float4 av = *(const float4*)&sA[(ty * 4 + i) * 68 + m];
        a_[i][0] = av.x; a_[i][1] = av.y; a_[i][2] = av.z; a_[i][3] = av.w;
      }
      #pragma unroll
      for (int mm = 0; mm < 4; ++mm) {
        float4 bv = *(const float4*)&sB[(m + mm) * 132 + u0];
        #pragma unroll
        for (int i = 0; i < 4; ++i) {
          acc[i][0] = fmaf(a_[i][mm], bv.x, acc[i][0]);
          acc[i][1] = fmaf(a_[i][mm], bv.y, acc[i][1]);
          acc[i][2] = fmaf(a_[i][mm], bv.z, acc[i][2]);
          acc[i][3] = fmaf(a_[i][mm], bv.w, acc[i][3]);
        }
      }
    }
    __syncthreads();
  }

  // ---- epilogue: s = pm + bm + pq + pl ----
  const float4 bm4 = *(const float4*)&bm[u0];
  const float4 pq4 = *(const float4*)&pq[b * Uv + u0];
  const float4 b24 = *(const float4*)&bias2g[u0];

  float sval[4][4];
  #pragma unroll
  for (int i = 0; i < 4; ++i) {
    sval[i][0] = acc[i][0] + bm4.x + pq4.x + b24.x;
    sval[i][1] = acc[i][1] + bm4.y + pq4.y + b24.y;
    sval[i][2] = acc[i][2] + bm4.z + pq4.z + b24.z;
    sval[i][3] = acc[i][3] + bm4.w + pq4.w + b24.w;
  }
  for (int k = 0; k < 31; ++k) {
    float4 w2 = *(const float4*)&sW2[k * Uv + u0];
    #pragma unroll
    for (int i = 0; i < 4; ++i) {
      float st = sState[ty * 4 + i + 2 * k];
      sval[i][0] = fmaf(st, w2.x, sval[i][0]);
      sval[i][1] = fmaf(st, w2.y, sval[i][1]);
      sval[i][2] = fmaf(st, w2.z, sval[i][2]);
      sval[i][3] = fmaf(st, w2.w, sval[i][3]);
    }
  }
  #pragma unroll
  for (int i = 0; i < 4; ++i) {
    float4 v; v.x = sval[i][0]; v.y = sval[i][1]; v.z = sval[i][2]; v.w = sval[i][3];
    *(float4*)&sS[(ty * 4 + i) * 132 + u0] = v;
  }
  __syncthreads();

  // ---- second GEMM: e2 = s @ We + be ----
  float e2[4][4];
  const float4 be4 = *(const float4*)&be[u0];
  #pragma unroll
  for (int i = 0; i < 4; ++i) { e2[i][0] = be4.x; e2[i][1] = be4.y; e2[i][2] = be4.z; e2[i][3] = be4.w; }

  for (int u = 0; u < Uv; u += 4) {
    float s_[4][4];
    #pragma unroll
    for (int i = 0; i < 4; ++i) {
      float4 sv = *(const float4*)&sS[(ty * 4 + i) * 132 + u];
      s_[i][0] = sv.x; s_[i][1] = sv.y; s_[i][2] = sv.z; s_[i][3] = sv.w;
    }
    #pragma unroll
    for (int q = 0; q < 4; ++q) {
      float4 wv = *(const float4*)&We[(size_t)(u + q) * Uv + u0];
      #pragma unroll
      for (int i = 0; i < 4; ++i) {
        e2[i][0] = fmaf(s_[i][q], wv.x, e2[i][0]);
        e2[i][1] = fmaf(s_[i][q], wv.y, e2[i][1]);
        e2[i][2] = fmaf(s_[i][q], wv.z, e2[i][2]);
        e2[i][3] = fmaf(s_[i][q], wv.w, e2[i][3]);
      }
    }
  }

  // ---- energy = sum_u' va * tanh(e2), reduce across tx lanes ----
  const float4 va4 = *(const float4*)&va[u0];
  float p[4];
  #pragma unroll
  for (int i = 0; i < 4; ++i) {
    p[i] = va4.x * tanhf(e2[i][0]) + va4.y * tanhf(e2[i][1])
         + va4.z * tanhf(e2[i][2]) + va4.w * tanhf(e2[i][3]);
  }
  #pragma unroll
  for (int off = 16; off > 0; off >>= 1) {
    #pragma unroll
    for (int i = 0; i < 4; ++i) p[i] += __shfl_xor(p[i], off, 64);
  }

  // ---- sigmoid, accumulate P0 (prev_cum*pm), P1 (sg*pm), Ssg ----
  float c0[4] = {0.f, 0.f, 0.f, 0.f}, c1[4] = {0.f, 0.f, 0.f, 0.f};
  float sgsum = 0.0f;
  #pragma unroll
  for (int i = 0; i < 4; ++i) {
    int t = t0 + ty * 4 + i;
    float sg = 1.0f / (1.0f + expf(-p[i]));
    float pc = prev_cum[b * Tv + t];
    sgsum += sg;
    float pm0 = acc[i][0] + bm4.x;
    float pm1 = acc[i][1] + bm4.y;
    float pm2 = acc[i][2] + bm4.z;
    float pm3 = acc[i][3] + bm4.w;
    c0[0] = fmaf(pc, pm0, c0[0]); c1[0] = fmaf(sg, pm0, c1[0]);
    c0[1] = fmaf(pc, pm1, c0[1]); c1[1] = fmaf(sg, pm1, c1[1]);
    c0[2] = fmaf(pc, pm2, c0[2]); c1[2] = fmaf(sg, pm2, c1[2]);
    c0[3] = fmaf(pc, pm3, c0[3]); c1[3] = fmaf(sg, pm3, c1[3]);
  }
  #pragma unroll
  for (int j = 0; j < 4; ++j) {
    atomicAdd(&blkP0[u0 + j], c0[j]);
    atomicAdd(&blkP1[u0 + j], c1[j]);
  }
  if (tx == 0) atomicAdd(&blkSsg, sgsum);
  __syncthreads();
  if (tid < Uv) {
    unsafeAtomicAdd(&P0[b * Uv + tid], blkP0[tid]);
    unsafeAtomicAdd(&P1[b * Uv + tid], blkP1[tid]);
  }
  if (tid == Uv) unsafeAtomicAdd(&Ssg[b], blkSsg);
}

// ---------------- finish: context = P0 + P1 / Ssg ----------------
__global__ __launch_bounds__(128) void finish_kernel(const float* __restrict__ P0,
                                                     const float* __restrict__ P1,
                                                     const float* __restrict__ Ssg,
                                                     float* __restrict__ out) {
  const int b = blockIdx.x, u = threadIdx.x;
  out[b * Uv + u] = P0[b * Uv + u] + P1[b * Uv + u] / Ssg[b];
}

extern "C" void kernel_launch(void* const* d_in, const int* in_sizes, int n_in,
                              void* d_out, int out_size, void* d_ws, size_t ws_size,
                              hipStream_t stream) {
  (void)in_sizes; (void)n_in; (void)out_size; (void)ws_size;
  const float* query    = (const float*)d_in[0];
  const float* state    = (const float*)d_in[1];
  const float* prev_cum = (const float*)d_in[2];
  const float* memory   = (const float*)d_in[3];
  const float* Wq       = (const float*)d_in[4];
  const float* bq       = (const float*)d_in[5];
  const float* Wm       = (const float*)d_in[6];
  const float* bm       = (const float*)d_in[7];
  const float* Wl       = (const float*)d_in[8];
  const float* bl       = (const float*)d_in[9];
  const float* We       = (const float*)d_in[10];
  const float* be       = (const float*)d_in[11];
  const float* va       = (const float*)d_in[12];
  const float* conv_w   = (const float*)d_in[13];
  const float* conv_b   = (const float*)d_in[14];

  float* ws    = (float*)d_ws;
  float* P0    = ws;            // 8192
  float* P1    = ws + 8192;     // 8192
  float* Ssg   = ws + 16384;    // 64
  float* pq    = ws + 16448;    // 8192
  float* W2    = ws + 24640;    // 3968
  float* bias2 = ws + 28608;    // 128

  // zero P0, P1, Ssg, pq (24640 floats)
  hipMemsetAsync(d_ws, 0, 24640 * sizeof(float), stream);

  pq_kernel<<<dim3(Bv, 8), 128, 0, stream>>>(query, Wq, bq, pq);
  w2_kernel<<<1, 128, 0, stream>>>(Wl, bl, conv_w, conv_b, W2, bias2);
  main_kernel<<<dim3(Tv / TTv, Bv), 256, 0, stream>>>(
      state, prev_cum, memory, Wm, bm, We, be, va, pq, W2, bias2, P0, P1, Ssg);
  finish_kernel<<<Bv, 128, 0, stream>>>(P0, P1, Ssg, (float*)d_out);
}

// Round 2
// 465.375 us; speedup vs baseline: 1.4973x; 1.4973x over previous
//
#include <hip/hip_runtime.h>

#define Bv 64
#define Tv 2048
#define Hv 1024
#define Uv 128
#define Mv 512

typedef __bf16 bf16x8 __attribute__((ext_vector_type(8)));
typedef float f32x4 __attribute__((ext_vector_type(4)));

union U4BF { uint4 u; bf16x8 b; };

#define MFMA(a, b, c) __builtin_amdgcn_mfma_f32_16x16x32_bf16((a), (b), (c), 0, 0, 0)

__device__ __forceinline__ unsigned short f2bf(float f) {
  __bf16 h = (__bf16)f;
  return __builtin_bit_cast(unsigned short, h);
}
__device__ __forceinline__ unsigned int pack2(unsigned short lo, unsigned short hi) {
  return (unsigned int)lo | ((unsigned int)hi << 16);
}

// ---------------- k1: pq[b,u] = query@Wq + bq  (bx<512)  |  W2/bias2 fold (bx==512) ----------------
__global__ __launch_bounds__(128) void k1_kernel(const float* __restrict__ query,
                                                 const float* __restrict__ Wq,
                                                 const float* __restrict__ bq,
                                                 const float* __restrict__ Wl,
                                                 const float* __restrict__ bl,
                                                 const float* __restrict__ conv_w,
                                                 const float* __restrict__ conv_b,
                                                 float* __restrict__ pq,
                                                 float* __restrict__ W2,
                                                 float* __restrict__ bias2) {
  const int bx = blockIdx.x;
  const int u = threadIdx.x;
  if (bx < 512) {
    const int b = bx >> 3, c = bx & 7;
    float acc = (c == 0) ? bq[u] : 0.0f;
    const float* q  = query + b * Hv + c * 128;
    const float* wq = Wq + (size_t)c * 128 * Uv;
    #pragma unroll 8
    for (int h = 0; h < 128; ++h) acc = fmaf(q[h], wq[h * Uv + u], acc);
    unsafeAtomicAdd(&pq[b * Uv + u], acc);
  } else {
    float wl[32];
    #pragma unroll
    for (int f = 0; f < 32; ++f) wl[f] = Wl[f * Uv + u];
    for (int k = 0; k < 31; ++k) {
      float acc = 0.0f;
      #pragma unroll
      for (int f = 0; f < 32; ++f) acc = fmaf(conv_w[f * 31 + k], wl[f], acc);
      W2[k * Uv + u] = acc;
    }
    float acc = bl[u];
    #pragma unroll
    for (int f = 0; f < 32; ++f) acc = fmaf(conv_b[f], wl[f], acc);
    bias2[u] = acc;
  }
}

// ---------------- k2: qe[b,n] = (pq[b]+bias2+bm)@We + be ;  w3tmp[k,n] = W2@We (rows 64..95) ----------------
__global__ __launch_bounds__(256) void k2_kernel(const float* __restrict__ pq,
                                                 const float* __restrict__ bias2,
                                                 const float* __restrict__ bm,
                                                 const float* __restrict__ be,
                                                 const float* __restrict__ We,
                                                 const float* __restrict__ W2,
                                                 float* __restrict__ qe,
                                                 float* __restrict__ w3tmp) {
  const int gtid = blockIdx.x * 256 + threadIdx.x;
  const int r = gtid >> 7, n = gtid & 127;
  if (r < 64) {
    float acc = be[n];
    for (int u = 0; u < Uv; ++u)
      acc = fmaf(pq[r * Uv + u] + bias2[u] + bm[u], We[u * Uv + n], acc);
    qe[r * Uv + n] = acc;
  } else {
    const int w = r - 64;
    float acc = 0.0f;
    if (w < 31) {
      for (int u = 0; u < Uv; ++u) acc = fmaf(W2[w * Uv + u], We[u * Uv + n], acc);
    }
    w3tmp[w * Uv + n] = acc;
  }
}

// ---------------- k3: pack Wm / We / w3tmp into bf16 MFMA B-fragment layout ----------------
// Fragment layout (16x16x32 bf16 B-operand): lane holds B[k = (lane>>4)*8 + j][n = lane&15].
// Stored as [frag][lane][8 bf16] so loads are lane*16B coalesced.
__global__ __launch_bounds__(256) void k3_kernel(const float* __restrict__ Wm,
                                                 const float* __restrict__ We,
                                                 const float* __restrict__ w3tmp,
                                                 unsigned short* __restrict__ WmF,
                                                 unsigned short* __restrict__ WeF,
                                                 unsigned short* __restrict__ W3F) {
  const int gtid = blockIdx.x * 256 + threadIdx.x;
  const int fid = gtid >> 6, lane = gtid & 63;
  const int quad = lane >> 4, l4 = lane & 15;
  float v[8];
  unsigned short* dst;
  if (fid < 128) {                    // Wm: 16 kc x 8 uj
    const int kc = fid >> 3, uj = fid & 7;
    #pragma unroll
    for (int j = 0; j < 8; ++j) v[j] = Wm[(size_t)(kc * 32 + quad * 8 + j) * Uv + uj * 16 + l4];
    dst = WmF + (size_t)fid * 512 + lane * 8;
  } else if (fid < 160) {             // We: 4 kc x 8 nj
    const int f2 = fid - 128;
    const int kc = f2 >> 3, nj = f2 & 7;
    #pragma unroll
    for (int j = 0; j < 8; ++j) v[j] = We[(size_t)(kc * 32 + quad * 8 + j) * Uv + nj * 16 + l4];
    dst = WeF + (size_t)f2 * 512 + lane * 8;
  } else {                            // W3: 1 kc x 8 nj (k=31 row already zeroed in w3tmp)
    const int nj = fid - 160;
    #pragma unroll
    for (int j = 0; j < 8; ++j) v[j] = w3tmp[(quad * 8 + j) * Uv + nj * 16 + l4];
    dst = W3F + (size_t)nj * 512 + lane * 8;
  }
  uint4 o;
  o.x = pack2(f2bf(v[0]), f2bf(v[1]));
  o.y = pack2(f2bf(v[2]), f2bf(v[3]));
  o.z = pack2(f2bf(v[4]), f2bf(v[5]));
  o.w = pack2(f2bf(v[6]), f2bf(v[7]));
  *(uint4*)dst = o;
}

// ---------------- main fused kernel ----------------
// Block = 64t x 128u of batch b. Phase 1: pm = memory@Wm via bf16 MFMA,
// A-frags loaded global->VGPR (fp32->bf16 cvt), B-frags from pre-packed WmF (L2).
// Phase 2: pm -> LDS bf16, e2 = pm@We + S2@W3 + qe[b] via MFMA, tanh/va-dot/sigmoid.
// Phase 3: P0 += prev_cum*pm_full, P1 += sg*pm_full, Ssg += sg (block reduce + atomics).
__global__ __launch_bounds__(256) void main_kernel(
    const float* __restrict__ memory, const unsigned short* __restrict__ WmF,
    const unsigned short* __restrict__ WeF, const unsigned short* __restrict__ W3F,
    const float* __restrict__ qe, const float* __restrict__ state,
    const float* __restrict__ prev_cum, const float* __restrict__ bm,
    const float* __restrict__ va,
    float* __restrict__ P0, float* __restrict__ P1, float* __restrict__ Ssg) {
  const int tid = threadIdx.x;
  const int lane = tid & 63, wid = tid >> 6;
  const int l4 = lane & 15, quad = lane >> 4;
  const int wt = wid >> 1, wu = wid & 1;
  const int b = blockIdx.y, t0 = blockIdx.x * 64;

  __shared__ float sState[124];
  __shared__ float sPc[64];
  __shared__ float sBm[128];
  __shared__ float sVa[128];
  __shared__ float sSg[64];
  __shared__ float blkP0[128], blkP1[128];
  __shared__ float blkSsg;
  __shared__ __align__(16) unsigned short sS[64 * 144];  // pm tile bf16, row stride 144

  for (int i = tid; i < 124; i += 256) {
    int t = t0 - 30 + i;
    sState[i] = (t >= 0 && t < Tv) ? state[b * Tv + t] : 0.0f;
  }
  if (tid < 64) sPc[tid] = prev_cum[b * Tv + t0 + tid];
  for (int i = tid; i < 128; i += 256) {
    sBm[i] = bm[i]; sVa[i] = va[i]; blkP0[i] = 0.0f; blkP1[i] = 0.0f;
  }
  if (tid == 0) blkSsg = 0.0f;

  // ---- phase 1: pm GEMM. wave (wt,wu): t-range wt*32..+32 (2 tiles), u-range wu*64..+64 (4 tiles)
  f32x4 acc[2][4];
  #pragma unroll
  for (int ti = 0; ti < 2; ++ti)
    #pragma unroll
    for (int uj = 0; uj < 4; ++uj) acc[ti][uj] = (f32x4){0.f, 0.f, 0.f, 0.f};

  const float* aBase = memory + ((size_t)b * Tv + t0 + wt * 32 + l4) * Mv + quad * 8;
  const unsigned short* bBase = WmF + (size_t)(wu * 4) * 512 + lane * 8;

  for (int kc = 0; kc < 16; ++kc) {
    float4 a0 = *(const float4*)(aBase + kc * 32);
    float4 a1 = *(const float4*)(aBase + kc * 32 + 4);
    float4 a2 = *(const float4*)(aBase + (size_t)16 * Mv + kc * 32);
    float4 a3 = *(const float4*)(aBase + (size_t)16 * Mv + kc * 32 + 4);
    U4BF bf[4];
    #pragma unroll
    for (int uj = 0; uj < 4; ++uj)
      bf[uj].u = *(const uint4*)(bBase + (size_t)(kc * 8 + uj) * 512);
    bf16x8 af0, af1;
    af0[0] = (__bf16)a0.x; af0[1] = (__bf16)a0.y; af0[2] = (__bf16)a0.z; af0[3] = (__bf16)a0.w;
    af0[4] = (__bf16)a1.x; af0[5] = (__bf16)a1.y; af0[6] = (__bf16)a1.z; af0[7] = (__bf16)a1.w;
    af1[0] = (__bf16)a2.x; af1[1] = (__bf16)a2.y; af1[2] = (__bf16)a2.z; af1[3] = (__bf16)a2.w;
    af1[4] = (__bf16)a3.x; af1[5] = (__bf16)a3.y; af1[6] = (__bf16)a3.z; af1[7] = (__bf16)a3.w;
    #pragma unroll
    for (int uj = 0; uj < 4; ++uj) {
      acc[0][uj] = MFMA(af0, bf[uj].b, acc[0][uj]);
      acc[1][uj] = MFMA(af1, bf[uj].b, acc[1][uj]);
    }
  }

  // ---- write pm (bf16) to LDS; C layout: col=lane&15, row=quad*4+reg
  #pragma unroll
  for (int ti = 0; ti < 2; ++ti) {
    const int rowb = wt * 32 + ti * 16 + quad * 4;
    #pragma unroll
    for (int uj = 0; uj < 4; ++uj) {
      const int col = wu * 64 + uj * 16 + l4;
      #pragma unroll
      for (int r = 0; r < 4; ++r) sS[(rowb + r) * 144 + col] = f2bf(acc[ti][uj][r]);
    }
  }
  __syncthreads();

  // ---- phase 2: e2 = pm@We + S2@W3 + qe[b]; wave wid owns t-rows wid*16..+16, all 128 n
  const int w = wid;
  f32x4 e[8];
  #pragma unroll
  for (int nj = 0; nj < 8; ++nj) {
    float qv = qe[b * Uv + nj * 16 + l4];
    e[nj] = (f32x4){qv, qv, qv, qv};
  }
  // S2 A-frag: S2[t][k] = state[t - 30 + 2k] (window), k=31 zero-pad
  bf16x8 a2f;
  #pragma unroll
  for (int j = 0; j < 8; ++j) {
    int k = quad * 8 + j;
    float v = (k < 31) ? sState[(w * 16 + l4) + 2 * k] : 0.0f;
    a2f[j] = (__bf16)v;
  }
  #pragma unroll
  for (int nj = 0; nj < 8; ++nj) {
    U4BF bb; bb.u = *(const uint4*)(W3F + (size_t)nj * 512 + lane * 8);
    e[nj] = MFMA(a2f, bb.b, e[nj]);
  }
  #pragma unroll
  for (int ks = 0; ks < 4; ++ks) {
    U4BF au;
    au.u = *(const uint4*)&sS[(w * 16 + l4) * 144 + ks * 32 + quad * 8];
    #pragma unroll
    for (int nj = 0; nj < 8; ++nj) {
      U4BF bb; bb.u = *(const uint4*)(WeF + (size_t)(ks * 8 + nj) * 512 + lane * 8);
      e[nj] = MFMA(au.b, bb.b, e[nj]);
    }
  }
  // energy rows: w*16 + quad*4 + r
  float p[4] = {0.f, 0.f, 0.f, 0.f};
  #pragma unroll
  for (int nj = 0; nj < 8; ++nj) {
    float vav = sVa[nj * 16 + l4];
    #pragma unroll
    for (int r = 0; r < 4; ++r) p[r] = fmaf(vav, tanhf(e[nj][r]), p[r]);
  }
  #pragma unroll
  for (int off = 1; off <= 8; off <<= 1) {
    #pragma unroll
    for (int r = 0; r < 4; ++r) p[r] += __shfl_xor(p[r], off, 64);
  }
  float sgv4[4], sgsum = 0.f;
  #pragma unroll
  for (int r = 0; r < 4; ++r) {
    sgv4[r] = 1.0f / (1.0f + expf(-p[r]));
    sgsum += sgv4[r];
  }
  if (l4 == 0) {
    #pragma unroll
    for (int r = 0; r < 4; ++r) sSg[w * 16 + quad * 4 + r] = sgv4[r];
    atomicAdd(&blkSsg, sgsum);
  }
  __syncthreads();

  // ---- phase 3: P0/P1 accumulation from pm accumulators
  float sgl[8], pcl[8];
  #pragma unroll
  for (int ti = 0; ti < 2; ++ti)
    #pragma unroll
    for (int r = 0; r < 4; ++r) {
      int row = wt * 32 + ti * 16 + quad * 4 + r;
      sgl[ti * 4 + r] = sSg[row];
      pcl[ti * 4 + r] = sPc[row];
    }
  #pragma unroll
  for (int uj = 0; uj < 4; ++uj) {
    const int col = wu * 64 + uj * 16 + l4;
    const float bmv = sBm[col];
    float c0 = 0.f, c1 = 0.f;
    #pragma unroll
    for (int ti = 0; ti < 2; ++ti)
      #pragma unroll
      for (int r = 0; r < 4; ++r) {
        float pmv = acc[ti][uj][r] + bmv;
        c0 = fmaf(pcl[ti * 4 + r], pmv, c0);
        c1 = fmaf(sgl[ti * 4 + r], pmv, c1);
      }
    c0 += __shfl_xor(c0, 16, 64); c0 += __shfl_xor(c0, 32, 64);
    c1 += __shfl_xor(c1, 16, 64); c1 += __shfl_xor(c1, 32, 64);
    if (quad == 0) {
      atomicAdd(&blkP0[col], c0);
      atomicAdd(&blkP1[col], c1);
    }
  }
  __syncthreads();
  if (tid < 128) {
    unsafeAtomicAdd(&P0[b * Uv + tid], blkP0[tid]);
    unsafeAtomicAdd(&P1[b * Uv + tid], blkP1[tid]);
  }
  if (tid == 0) unsafeAtomicAdd(&Ssg[b], blkSsg);
}

// ---------------- finish: context = P0 + P1 / Ssg ----------------
__global__ __launch_bounds__(128) void finish_kernel(const float* __restrict__ P0,
                                                     const float* __restrict__ P1,
                                                     const float* __restrict__ Ssg,
                                                     float* __restrict__ out) {
  const int b = blockIdx.x, u = threadIdx.x;
  out[b * Uv + u] = P0[b * Uv + u] + P1[b * Uv + u] / Ssg[b];
}

extern "C" void kernel_launch(void* const* d_in, const int* in_sizes, int n_in,
                              void* d_out, int out_size, void* d_ws, size_t ws_size,
                              hipStream_t stream) {
  (void)in_sizes; (void)n_in; (void)out_size; (void)ws_size;
  const float* query    = (const float*)d_in[0];
  const float* state    = (const float*)d_in[1];
  const float* prev_cum = (const float*)d_in[2];
  const float* memory   = (const float*)d_in[3];
  const float* Wq       = (const float*)d_in[4];
  const float* bq       = (const float*)d_in[5];
  const float* Wm       = (const float*)d_in[6];
  const float* bm       = (const float*)d_in[7];
  const float* Wl       = (const float*)d_in[8];
  const float* bl       = (const float*)d_in[9];
  const float* We       = (const float*)d_in[10];
  const float* be       = (const float*)d_in[11];
  const float* va       = (const float*)d_in[12];
  const float* conv_w   = (const float*)d_in[13];
  const float* conv_b   = (const float*)d_in[14];

  float* ws = (float*)d_ws;
  float* P0    = ws;                 // 8192
  float* P1    = ws + 8192;          // 8192
  float* Ssg   = ws + 16384;         // 64
  float* pq    = ws + 16448;         // 8192
  float* W2    = ws + 24640;         // 3968
  float* bias2 = ws + 28608;         // 128
  float* qe    = ws + 28736;         // 8192
  float* w3tmp = ws + 36928;         // 4096 (32x128, row 31 zeroed)
  unsigned short* WmF = (unsigned short*)(ws + 41024);  // 65536 bf16
  unsigned short* WeF = (unsigned short*)(ws + 73792);  // 16384 bf16
  unsigned short* W3F = (unsigned short*)(ws + 81984);  // 4096 bf16
  // total: 84032 floats = 336 KB

  // zero P0, P1, Ssg, pq
  hipMemsetAsync(d_ws, 0, 24640 * sizeof(float), stream);

  k1_kernel<<<513, 128, 0, stream>>>(query, Wq, bq, Wl, bl, conv_w, conv_b, pq, W2, bias2);
  k2_kernel<<<48, 256, 0, stream>>>(pq, bias2, bm, be, We, W2, qe, w3tmp);
  k3_kernel<<<42, 256, 0, stream>>>(Wm, We, w3tmp, WmF, WeF, W3F);
  main_kernel<<<dim3(Tv / 64, Bv), 256, 0, stream>>>(
      memory, WmF, WeF, W3F, qe, state, prev_cum, bm, va, P0, P1, Ssg);
  finish_kernel<<<Bv, 128, 0, stream>>>(P0, P1, Ssg, (float*)d_out);
}